// Round 1
// baseline (533.399 us; speedup 1.0000x reference)
//
#include <hip/hip_runtime.h>
#include <hip/hip_bf16.h>
#include <math.h>

// NetVLAD: B=16, H=W=56 (HW=3136), D=512, K=32, fp32.
// Plan (round 0, unfused for correctness + per-stage profiling):
//   K1 k_assign : s = x.Wc (per-position dots), softmax over K -> a (ws),
//                 block-reduced a_sum accumulated via fp32 HW atomics.
//   K2 k_ax     : ax[b,d,k] = sum_hw a*x, per-batch split-K GEMM,
//                 8x8 register tiles, LDS-staged 28-pos chunks,
//                 accumulate via unsafeAtomicAdd into vpart (1 MB, L2-resident).
//   K3 k_norm1  : v = vpart + C*a_sum, L2-normalize each (b,d,:) row,
//                 write to out, accumulate per-batch sum-of-squares.
//   K4 k_norm2  : out *= 1/max(sqrt(ssq[b]), 1e-12).

#define BATCH 16
#define HW    3136
#define DIM   512
#define KCL   32

__device__ __forceinline__ void atomAddF(float* p, float v) {
    unsafeAtomicAdd(p, v);   // global_atomic_add_f32 (device scope, HW fp32 add)
}

// ---------------- K1: assignment + softmax ----------------
// grid (13, 16), block 256. Each thread = one spatial position.
__global__ __launch_bounds__(256) void k_assign(const float* __restrict__ x,
                                                const float* __restrict__ Wc,
                                                float* __restrict__ a,
                                                float* __restrict__ a_sum) {
    __shared__ float xs[256 * 33];   // 256 rows x 32 cols, pad 33 -> 2-way (free)
    const int t = threadIdx.x;
    const int b = blockIdx.y;
    const int pos0 = blockIdx.x * 256;
    const int posb = pos0 + t;
    const bool active = posb < HW;
    const int nrows = min(256, HW - pos0);

    float acc[KCL];
#pragma unroll
    for (int k = 0; k < KCL; ++k) acc[k] = 0.f;

    for (int dc = 0; dc < DIM; dc += 32) {
        __syncthreads();
        // stage x[pos0..pos0+255][dc..dc+31], coalesced float4 loads
#pragma unroll
        for (int i = 0; i < 8; ++i) {
            int f = i * 256 + t;        // 0..2047
            int row = f >> 3;           // 0..255
            int c4 = (f & 7) * 4;       // 0..28
            float4 v = make_float4(0.f, 0.f, 0.f, 0.f);
            if (row < nrows) {
                const float* g = x + ((size_t)(b * HW + pos0 + row) * DIM + dc + c4);
                v = *(const float4*)g;
            }
            float* dst = &xs[row * 33 + c4];
            dst[0] = v.x; dst[1] = v.y; dst[2] = v.z; dst[3] = v.w;
        }
        __syncthreads();
        // Wc indices are wave-uniform -> s_load + v_fma(sgpr)
        const float* wrow = Wc + (size_t)dc * KCL;
#pragma unroll
        for (int dd = 0; dd < 32; ++dd) {
            float xv = xs[t * 33 + dd];
#pragma unroll
            for (int k = 0; k < KCL; ++k)
                acc[k] = fmaf(xv, wrow[dd * KCL + k], acc[k]);
        }
    }

    // softmax over K=32 (in registers)
    float m = -1e30f;
#pragma unroll
    for (int k = 0; k < KCL; ++k) m = fmaxf(m, acc[k]);
    float s = 0.f;
#pragma unroll
    for (int k = 0; k < KCL; ++k) { acc[k] = __expf(acc[k] - m); s += acc[k]; }
    float inv = 1.f / s;
#pragma unroll
    for (int k = 0; k < KCL; ++k) acc[k] = active ? acc[k] * inv : 0.f;

    if (active) {
        float* dst = a + (size_t)(b * HW + posb) * KCL;
#pragma unroll
        for (int k = 0; k < KCL; k += 4) {
            float4 v = make_float4(acc[k], acc[k + 1], acc[k + 2], acc[k + 3]);
            *(float4*)(dst + k) = v;
        }
    }

    // a_sum[b][k] += sum over positions: wave butterfly then 1 atomic set/wave
#pragma unroll
    for (int k = 0; k < KCL; ++k) {
        float v = acc[k];
        for (int off = 32; off > 0; off >>= 1) v += __shfl_down(v, off, 64);
        acc[k] = v;
    }
    if ((t & 63) == 0) {
#pragma unroll
        for (int k = 0; k < KCL; ++k) atomAddF(&a_sum[b * KCL + k], acc[k]);
    }
}

// ---------------- K2: ax GEMM (split-K over hw) ----------------
// grid (32, 16), block 256. Block s of batch b: chunks {s, s+32, s+64, (s+96)}.
// Each chunk = 28 positions (112 * 28 == 3136 exactly).
__global__ __launch_bounds__(256) void k_ax(const float* __restrict__ x,
                                            const float* __restrict__ a,
                                            float* __restrict__ vpart) {
    __shared__ float xs[28 * 512];   // 57344 B, rows 16B-aligned
    __shared__ float as_[28 * 32];   // 3584 B
    const int t = threadIdx.x;
    const int b = blockIdx.y;
    const int s = blockIdx.x;        // 0..31

    const int d0 = (t >> 2) * 8;     // 0..504
    const int k0 = (t & 3) * 8;      // 0,8,16,24

    float acc[8][8];
#pragma unroll
    for (int i = 0; i < 8; ++i)
#pragma unroll
        for (int j = 0; j < 8; ++j) acc[i][j] = 0.f;

    for (int chunk = s; chunk < 112; chunk += 32) {
        const int pos0 = chunk * 28;
        __syncthreads();
        // stage x: 28 x 512 floats, fully coalesced float4
#pragma unroll
        for (int i = 0; i < 14; ++i) {
            int f = i * 256 + t;      // 0..3583
            int pos = f >> 7;         // 0..27
            int c4 = (f & 127) * 4;   // 0..508
            float4 v = *(const float4*)(x + ((size_t)(b * HW + pos0 + pos) * DIM + c4));
            *(float4*)&xs[pos * 512 + c4] = v;
        }
        // stage a: 28 x 32 floats
        if (t < 224) {
            int pos = t >> 3;
            int k4 = (t & 7) * 4;
            *(float4*)&as_[pos * 32 + k4] =
                *(const float4*)(a + ((size_t)(b * HW + pos0 + pos) * KCL + k4));
        }
        __syncthreads();
#pragma unroll 4
        for (int p = 0; p < 28; ++p) {
            float4 xA = *(const float4*)&xs[p * 512 + d0];
            float4 xB = *(const float4*)&xs[p * 512 + d0 + 4];
            float4 aA = *(const float4*)&as_[p * 32 + k0];
            float4 aB = *(const float4*)&as_[p * 32 + k0 + 4];
            float xv[8] = {xA.x, xA.y, xA.z, xA.w, xB.x, xB.y, xB.z, xB.w};
            float av[8] = {aA.x, aA.y, aA.z, aA.w, aB.x, aB.y, aB.z, aB.w};
#pragma unroll
            for (int i = 0; i < 8; ++i)
#pragma unroll
                for (int j = 0; j < 8; ++j)
                    acc[i][j] = fmaf(xv[i], av[j], acc[i][j]);
        }
    }
#pragma unroll
    for (int i = 0; i < 8; ++i)
#pragma unroll
        for (int j = 0; j < 8; ++j)
            atomAddF(&vpart[((size_t)(b * DIM + d0 + i)) * KCL + k0 + j], acc[i][j]);
}

// ---------------- K3: v = vpart + C*a_sum, intra-normalize ----------------
// grid 32, block 256: one thread per (b,d) row of 32 clusters.
__global__ __launch_bounds__(256) void k_norm1(const float* __restrict__ vpart,
                                               const float* __restrict__ a_sum,
                                               const float* __restrict__ Cc,
                                               float* __restrict__ out,
                                               float* __restrict__ ssq) {
    const int t = threadIdx.x;
    const int row = blockIdx.x * 256 + t;   // 0..8191; block stays in one batch
    const int b = row >> 9;
    const int d = row & 511;
    float v[KCL];
    float ss = 0.f;
#pragma unroll
    for (int k = 0; k < KCL; ++k) {
        float val = vpart[(size_t)row * KCL + k] + Cc[d * KCL + k] * a_sum[b * KCL + k];
        v[k] = val;
        ss += val * val;
    }
    float inv = 1.f / fmaxf(sqrtf(ss), 1e-12f);
    float bs = 0.f;
#pragma unroll
    for (int k = 0; k < KCL; ++k) {
        float r = v[k] * inv;
        out[(size_t)row * KCL + k] = r;
        bs += r * r;
    }
    __shared__ float red[4];
    for (int off = 32; off > 0; off >>= 1) bs += __shfl_down(bs, off, 64);
    if ((t & 63) == 0) red[t >> 6] = bs;
    __syncthreads();
    if (t == 0) atomAddF(&ssq[b], red[0] + red[1] + red[2] + red[3]);
}

// ---------------- K4: final global L2 normalize ----------------
// grid 256, block 256, one float4 per thread (65536 float4s).
__global__ __launch_bounds__(256) void k_norm2(float* __restrict__ out,
                                               const float* __restrict__ ssq) {
    const int i4 = blockIdx.x * 256 + threadIdx.x;  // 0..65535
    const int b = i4 >> 12;                         // 4096 float4 per batch
    float inv = 1.f / fmaxf(sqrtf(ssq[b]), 1e-12f);
    float4 v = *(float4*)(out + (size_t)i4 * 4);
    v.x *= inv; v.y *= inv; v.z *= inv; v.w *= inv;
    *(float4*)(out + (size_t)i4 * 4) = v;
}

extern "C" void kernel_launch(void* const* d_in, const int* in_sizes, int n_in,
                              void* d_out, int out_size, void* d_ws, size_t ws_size,
                              hipStream_t stream) {
    const float* x  = (const float*)d_in[0];   // (16,56,56,512)
    const float* Wc = (const float*)d_in[1];   // (512,32)
    const float* Cc = (const float*)d_in[2];   // (512,32)
    float* out = (float*)d_out;                // (16, 16384)

    // workspace layout (bytes):
    //   a     : N*K*4          = 6,422,528
    //   vpart : B*D*K*4        = 1,048,576   } zeroed together
    //   a_sum : B*K*4          = 2,048       }
    //   ssq   : B*4            = 64          }
    char* ws = (char*)d_ws;
    float* a     = (float*)ws;
    float* vpart = (float*)(ws + 6422528);
    float* a_sum = (float*)(ws + 6422528 + 1048576);
    float* ssq   = (float*)(ws + 6422528 + 1048576 + 2048);

    hipMemsetAsync(vpart, 0, 1048576 + 2048 + 64, stream);

    k_assign<<<dim3(13, 16), 256, 0, stream>>>(x, Wc, a, a_sum);
    k_ax    <<<dim3(32, 16), 256, 0, stream>>>(x, a, vpart);
    k_norm1 <<<32,  256, 0, stream>>>(vpart, a_sum, Cc, out, ssq);
    k_norm2 <<<256, 256, 0, stream>>>(out, ssq);
}

// Round 2
// 341.781 us; speedup vs baseline: 1.5606x; 1.5606x over previous
//
#include <hip/hip_runtime.h>
#include <hip/hip_bf16.h>
#include <math.h>

// NetVLAD: B=16, H=W=56 (HW=3136), D=512, K=32, fp32.
// Round 2: kill the k_ax device-scope atomics (268 MB of 32B write-through
// transactions = the 240us bottleneck). Each split now stores its partial
// tile to a private vpart[s] slab; k_norm1 does the 32-way split reduction.
//   K1 k_assign : s = x.Wc per position, softmax -> a (ws), a_sum atomics (tiny).
//   K2 k_ax     : split-K GEMM, 8x8 reg tiles, stores partials to vpart[s].
//   K3 k_norm1  : sum 32 splits + C*a_sum, intra-normalize rows, batch ssq.
//   K4 k_norm2  : out *= 1/max(sqrt(ssq[b]), 1e-12).

#define BATCH 16
#define HW    3136
#define DIM   512
#define KCL   32
#define SPLITS 32

__device__ __forceinline__ void atomAddF(float* p, float v) {
    unsafeAtomicAdd(p, v);   // global_atomic_add_f32
}

// ---------------- K1: assignment + softmax ----------------
// grid (13, 16), block 256. Each thread = one spatial position.
__global__ __launch_bounds__(256) void k_assign(const float* __restrict__ x,
                                                const float* __restrict__ Wc,
                                                float* __restrict__ a,
                                                float* __restrict__ a_sum) {
    __shared__ float xs[256 * 33];   // pad 33 -> (t+dd)%32 banks, 2-way = free
    const int t = threadIdx.x;
    const int b = blockIdx.y;
    const int pos0 = blockIdx.x * 256;
    const int posb = pos0 + t;
    const bool active = posb < HW;
    const int nrows = min(256, HW - pos0);

    float acc[KCL];
#pragma unroll
    for (int k = 0; k < KCL; ++k) acc[k] = 0.f;

    for (int dc = 0; dc < DIM; dc += 32) {
        __syncthreads();
#pragma unroll
        for (int i = 0; i < 8; ++i) {
            int f = i * 256 + t;
            int row = f >> 3;
            int c4 = (f & 7) * 4;
            float4 v = make_float4(0.f, 0.f, 0.f, 0.f);
            if (row < nrows) {
                const float* g = x + ((size_t)(b * HW + pos0 + row) * DIM + dc + c4);
                v = *(const float4*)g;
            }
            float* dst = &xs[row * 33 + c4];
            dst[0] = v.x; dst[1] = v.y; dst[2] = v.z; dst[3] = v.w;
        }
        __syncthreads();
        // Wc indices wave-uniform -> scalar loads + v_fma(sgpr)
        const float* wrow = Wc + (size_t)dc * KCL;
#pragma unroll
        for (int dd = 0; dd < 32; ++dd) {
            float xv = xs[t * 33 + dd];
#pragma unroll
            for (int k = 0; k < KCL; ++k)
                acc[k] = fmaf(xv, wrow[dd * KCL + k], acc[k]);
        }
    }

    float m = -1e30f;
#pragma unroll
    for (int k = 0; k < KCL; ++k) m = fmaxf(m, acc[k]);
    float s = 0.f;
#pragma unroll
    for (int k = 0; k < KCL; ++k) { acc[k] = __expf(acc[k] - m); s += acc[k]; }
    float inv = 1.f / s;
#pragma unroll
    for (int k = 0; k < KCL; ++k) acc[k] = active ? acc[k] * inv : 0.f;

    if (active) {
        float* dst = a + (size_t)(b * HW + posb) * KCL;
#pragma unroll
        for (int k = 0; k < KCL; k += 4) {
            float4 v = make_float4(acc[k], acc[k + 1], acc[k + 2], acc[k + 3]);
            *(float4*)(dst + k) = v;
        }
    }

#pragma unroll
    for (int k = 0; k < KCL; ++k) {
        float v = acc[k];
        for (int off = 32; off > 0; off >>= 1) v += __shfl_down(v, off, 64);
        acc[k] = v;
    }
    if ((t & 63) == 0) {
#pragma unroll
        for (int k = 0; k < KCL; ++k) atomAddF(&a_sum[b * KCL + k], acc[k]);
    }
}

// ---------------- K2: ax GEMM (split-K over hw, private partial slabs) ------
// grid (32, 16), block 256. Split s of batch b handles chunks {s, s+32, ...}.
// 112 chunks of 28 positions (112*28 == 3136). Stores 8x8 tile to vpart[s].
__global__ __launch_bounds__(256) void k_ax(const float* __restrict__ x,
                                            const float* __restrict__ a,
                                            float* __restrict__ vpart) {
    __shared__ float xs[28 * 512];   // 57344 B
    __shared__ float as_[28 * 32];   // 3584 B
    const int t = threadIdx.x;
    const int b = blockIdx.y;
    const int s = blockIdx.x;        // 0..31

    const int d0 = (t >> 2) * 8;     // 0..504
    const int k0 = (t & 3) * 8;      // 0,8,16,24

    float acc[8][8];
#pragma unroll
    for (int i = 0; i < 8; ++i)
#pragma unroll
        for (int j = 0; j < 8; ++j) acc[i][j] = 0.f;

    for (int chunk = s; chunk < 112; chunk += SPLITS) {
        const int pos0 = chunk * 28;
        __syncthreads();
#pragma unroll
        for (int i = 0; i < 14; ++i) {
            int f = i * 256 + t;
            int pos = f >> 7;
            int c4 = (f & 127) * 4;
            float4 v = *(const float4*)(x + ((size_t)(b * HW + pos0 + pos) * DIM + c4));
            *(float4*)&xs[pos * 512 + c4] = v;
        }
        if (t < 224) {
            int pos = t >> 3;
            int k4 = (t & 7) * 4;
            *(float4*)&as_[pos * 32 + k4] =
                *(const float4*)(a + ((size_t)(b * HW + pos0 + pos) * KCL + k4));
        }
        __syncthreads();
#pragma unroll 4
        for (int p = 0; p < 28; ++p) {
            float4 xA = *(const float4*)&xs[p * 512 + d0];
            float4 xB = *(const float4*)&xs[p * 512 + d0 + 4];
            float4 aA = *(const float4*)&as_[p * 32 + k0];
            float4 aB = *(const float4*)&as_[p * 32 + k0 + 4];
            float xv[8] = {xA.x, xA.y, xA.z, xA.w, xB.x, xB.y, xB.z, xB.w};
            float av[8] = {aA.x, aA.y, aA.z, aA.w, aB.x, aB.y, aB.z, aB.w};
#pragma unroll
            for (int i = 0; i < 8; ++i)
#pragma unroll
                for (int j = 0; j < 8; ++j)
                    acc[i][j] = fmaf(xv[i], av[j], acc[i][j]);
        }
    }
    // plain coalesced stores to this split's private slab (no atomics)
    float* vp = vpart + ((size_t)s * BATCH * DIM + (size_t)b * DIM) * KCL;
#pragma unroll
    for (int i = 0; i < 8; ++i) {
        float* row = vp + (size_t)(d0 + i) * KCL + k0;
        *(float4*)(row)     = make_float4(acc[i][0], acc[i][1], acc[i][2], acc[i][3]);
        *(float4*)(row + 4) = make_float4(acc[i][4], acc[i][5], acc[i][6], acc[i][7]);
    }
}

// ---------------- K3: split-reduce + C*a_sum + intra-normalize ----------------
// grid 256, block 256: 32 rows per block, 8 threads per row, float4 per thread.
__global__ __launch_bounds__(256) void k_norm1(const float* __restrict__ vpart,
                                               const float* __restrict__ a_sum,
                                               const float* __restrict__ Cc,
                                               float* __restrict__ out,
                                               float* __restrict__ ssq) {
    const int t = threadIdx.x;
    const int row = blockIdx.x * 32 + (t >> 3);  // 0..8191 (block = one batch slice)
    const int c = (t & 7) * 4;                   // 0,4,...,28
    const int b = row >> 9;
    const int d = row & 511;

    float4 sum = make_float4(0.f, 0.f, 0.f, 0.f);
#pragma unroll 8
    for (int s = 0; s < SPLITS; ++s) {
        float4 p = *(const float4*)(vpart + (((size_t)s * BATCH * DIM + row) * KCL + c));
        sum.x += p.x; sum.y += p.y; sum.z += p.z; sum.w += p.w;
    }
    float4 cc = *(const float4*)(Cc + d * KCL + c);
    float4 as = *(const float4*)(a_sum + b * KCL + c);
    float4 v;
    v.x = sum.x + cc.x * as.x;
    v.y = sum.y + cc.y * as.y;
    v.z = sum.z + cc.z * as.z;
    v.w = sum.w + cc.w * as.w;

    float part = v.x * v.x + v.y * v.y + v.z * v.z + v.w * v.w;
    float ss = part;
    ss += __shfl_xor(ss, 1, 8);
    ss += __shfl_xor(ss, 2, 8);
    ss += __shfl_xor(ss, 4, 8);
    float inv = 1.f / fmaxf(sqrtf(ss), 1e-12f);
    v.x *= inv; v.y *= inv; v.z *= inv; v.w *= inv;
    *(float4*)(out + (size_t)row * KCL + c) = v;

    // batch sum-of-squares of normalized values
    float bs = part * inv * inv;
    for (int off = 32; off > 0; off >>= 1) bs += __shfl_down(bs, off, 64);
    __shared__ float red[4];
    if ((t & 63) == 0) red[t >> 6] = bs;
    __syncthreads();
    if (t == 0) atomAddF(&ssq[b], red[0] + red[1] + red[2] + red[3]);
}

// ---------------- K4: final global L2 normalize ----------------
__global__ __launch_bounds__(256) void k_norm2(float* __restrict__ out,
                                               const float* __restrict__ ssq) {
    const int i4 = blockIdx.x * 256 + threadIdx.x;  // 0..65535
    const int b = i4 >> 12;
    float inv = 1.f / fmaxf(sqrtf(ssq[b]), 1e-12f);
    float4 v = *(float4*)(out + (size_t)i4 * 4);
    v.x *= inv; v.y *= inv; v.z *= inv; v.w *= inv;
    *(float4*)(out + (size_t)i4 * 4) = v;
}

extern "C" void kernel_launch(void* const* d_in, const int* in_sizes, int n_in,
                              void* d_out, int out_size, void* d_ws, size_t ws_size,
                              hipStream_t stream) {
    const float* x  = (const float*)d_in[0];   // (16,56,56,512)
    const float* Wc = (const float*)d_in[1];   // (512,32)
    const float* Cc = (const float*)d_in[2];   // (512,32)
    float* out = (float*)d_out;                // (16, 16384)

    // workspace layout (bytes):
    //   a     : N*K*4              = 6,422,528
    //   vpart : SPLITS*B*D*K*4     = 33,554,432  (pure stores, no init needed)
    //   a_sum : B*K*4              = 2,048   } zeroed
    //   ssq   : B*4                = 64      } zeroed
    char* ws = (char*)d_ws;
    float* a     = (float*)ws;
    float* vpart = (float*)(ws + 6422528);
    float* a_sum = (float*)(ws + 6422528 + 33554432);
    float* ssq   = (float*)(ws + 6422528 + 33554432 + 2048);

    hipMemsetAsync(a_sum, 0, 2048 + 64, stream);

    k_assign<<<dim3(13, 16), 256, 0, stream>>>(x, Wc, a, a_sum);
    k_ax    <<<dim3(SPLITS, 16), 256, 0, stream>>>(x, a, vpart);
    k_norm1 <<<256, 256, 0, stream>>>(vpart, a_sum, Cc, out, ssq);
    k_norm2 <<<256, 256, 0, stream>>>(out, ssq);
}

// Round 3
// 252.204 us; speedup vs baseline: 2.1150x; 1.3552x over previous
//
#include <hip/hip_runtime.h>
#include <hip/hip_bf16.h>
#include <math.h>

// NetVLAD: B=16, H=W=56 (HW=3136), D=512, K=32, fp32.
// Round 3:
//   K1 k_assign REWRITE: wave = 8 clusters (k wave-uniform -> Wc via SGPR
//     s_loads), lane = position, x tile in LDS read as aligned b128.
//     Old version: 208 blocks (1 wave/SIMD) + scalar ds_read_b32 + per-FMA
//     vector operand loads = 184us latency-bound. New: 784 blocks, 12 w/CU.
//   K2 k_ax: chunk 28->14 positions: LDS 60.9->30.5 KB, 2->5 blocks/CU,
//     to hide barrier-synchronized staging latency. Math unchanged.
//   K3/K4 unchanged.

#define BATCH 16
#define HW    3136
#define DIM   512
#define KCL   32
#define SPLITS 32

__device__ __forceinline__ void atomAddF(float* p, float v) {
    unsafeAtomicAdd(p, v);   // global_atomic_add_f32
}

// ---------------- K1: assignment + softmax ----------------
// grid (49, 16), block 256 = 4 waves. Wave wv owns clusters [wv*8, wv*8+8);
// lane = position within the 64-position tile. 8 D-chunks of 64.
__global__ __launch_bounds__(256) void k_assign(const float* __restrict__ x,
                                                const float* __restrict__ Wc,
                                                float* __restrict__ a,
                                                float* __restrict__ a_sum) {
    __shared__ float xs[64 * 68];   // stride 68: b128 rows aligned, phases conflict-free
    __shared__ float red[4][64];
    const int t    = threadIdx.x;
    const int lane = t & 63;                 // position within tile
    const int wv   = t >> 6;                 // 0..3
    const int k0   = __builtin_amdgcn_readfirstlane(wv * 8);  // force SGPR
    const int b    = blockIdx.y;
    const int pos0 = blockIdx.x * 64;        // 49*64 == 3136 exactly

    float acc[8];
#pragma unroll
    for (int j = 0; j < 8; ++j) acc[j] = 0.f;

    for (int dc = 0; dc < DIM; dc += 64) {
        __syncthreads();
        // stage x[pos0..pos0+63][dc..dc+63]: 1024 float4 loads, 4 per thread
#pragma unroll
        for (int i = 0; i < 4; ++i) {
            int f = i * 256 + t;             // 0..1023
            int pos = f >> 4;                // 0..63
            int c4 = (f & 15) * 4;           // 0..60
            float4 v = *(const float4*)(x + ((size_t)(b * HW + pos0 + pos) * DIM + dc + c4));
            *(float4*)&xs[pos * 68 + c4] = v;
        }
        __syncthreads();
        const float* wp = Wc + (size_t)dc * KCL + k0;   // uniform base -> s_load
#pragma unroll
        for (int q = 0; q < 16; ++q) {       // 4 dd per quad
            float4 xq = *(const float4*)&xs[lane * 68 + q * 4];
            float xv[4] = {xq.x, xq.y, xq.z, xq.w};
#pragma unroll
            for (int i = 0; i < 4; ++i) {
#pragma unroll
                for (int j = 0; j < 8; ++j)
                    acc[j] = fmaf(xv[i], wp[(q * 4 + i) * KCL + j], acc[j]);
            }
        }
    }

    // ---- softmax over 32 k spread across 4 waves (same lane) ----
    float m8 = acc[0];
#pragma unroll
    for (int j = 1; j < 8; ++j) m8 = fmaxf(m8, acc[j]);
    red[wv][lane] = m8;
    __syncthreads();
    float m = fmaxf(fmaxf(red[0][lane], red[1][lane]), fmaxf(red[2][lane], red[3][lane]));
    __syncthreads();
    float s8 = 0.f;
#pragma unroll
    for (int j = 0; j < 8; ++j) { acc[j] = __expf(acc[j] - m); s8 += acc[j]; }
    red[wv][lane] = s8;
    __syncthreads();
    float inv = 1.f / (red[0][lane] + red[1][lane] + red[2][lane] + red[3][lane]);
#pragma unroll
    for (int j = 0; j < 8; ++j) acc[j] *= inv;

    // ---- repack through LDS (reuse xs) for coalesced a stores ----
    // as[pos][k], stride 36 floats (16B-aligned rows, conflict-free quads)
    float* as_ = xs;
    *(float4*)&as_[lane * 36 + k0]     = make_float4(acc[0], acc[1], acc[2], acc[3]);
    *(float4*)&as_[lane * 36 + k0 + 4] = make_float4(acc[4], acc[5], acc[6], acc[7]);

    // ---- a_sum: butterfly over lanes (positions), 8 atomics per wave ----
#pragma unroll
    for (int j = 0; j < 8; ++j) {
        float v = acc[j];
        v += __shfl_xor(v, 1);  v += __shfl_xor(v, 2);  v += __shfl_xor(v, 4);
        v += __shfl_xor(v, 8);  v += __shfl_xor(v, 16); v += __shfl_xor(v, 32);
        acc[j] = v;
    }
    if (lane == 0) {
#pragma unroll
        for (int j = 0; j < 8; ++j) atomAddF(&a_sum[b * KCL + k0 + j], acc[j]);
    }

    __syncthreads();
#pragma unroll
    for (int r = 0; r < 2; ++r) {
        int idx = r * 256 + t;               // 0..511
        int pos = idx >> 3;
        int c4 = (idx & 7) * 4;
        float4 v = *(const float4*)&as_[pos * 36 + c4];
        *(float4*)(a + ((size_t)(b * HW + pos0 + pos) * KCL + c4)) = v;
    }
}

// ---------------- K2: ax GEMM (split-K over hw, private partial slabs) ------
// grid (32, 16), block 256. 224 chunks of 14 positions (224*14 == 3136);
// split s handles chunks {s, s+32, ...} = 7 chunks. LDS 30.5 KB -> 5 blocks/CU.
__global__ __launch_bounds__(256) void k_ax(const float* __restrict__ x,
                                            const float* __restrict__ a,
                                            float* __restrict__ vpart) {
    __shared__ float xs[14 * 512];   // 28672 B
    __shared__ float as_[14 * 32];   // 1792 B
    const int t = threadIdx.x;
    const int b = blockIdx.y;
    const int s = blockIdx.x;        // 0..31

    const int d0 = (t >> 2) * 8;     // 0..504
    const int k0 = (t & 3) * 8;      // 0,8,16,24

    float acc[8][8];
#pragma unroll
    for (int i = 0; i < 8; ++i)
#pragma unroll
        for (int j = 0; j < 8; ++j) acc[i][j] = 0.f;

    for (int chunk = s; chunk < 224; chunk += SPLITS) {
        const int pos0 = chunk * 14;
        __syncthreads();
#pragma unroll
        for (int i = 0; i < 7; ++i) {
            int f = i * 256 + t;      // 0..1791
            int pos = f >> 7;         // 0..13
            int c4 = (f & 127) * 4;   // 0..508
            float4 v = *(const float4*)(x + ((size_t)(b * HW + pos0 + pos) * DIM + c4));
            *(float4*)&xs[pos * 512 + c4] = v;
        }
        if (t < 112) {
            int pos = t >> 3;
            int k4 = (t & 7) * 4;
            *(float4*)&as_[pos * 32 + k4] =
                *(const float4*)(a + ((size_t)(b * HW + pos0 + pos) * KCL + k4));
        }
        __syncthreads();
#pragma unroll 2
        for (int p = 0; p < 14; ++p) {
            float4 xA = *(const float4*)&xs[p * 512 + d0];
            float4 xB = *(const float4*)&xs[p * 512 + d0 + 4];
            float4 aA = *(const float4*)&as_[p * 32 + k0];
            float4 aB = *(const float4*)&as_[p * 32 + k0 + 4];
            float xv[8] = {xA.x, xA.y, xA.z, xA.w, xB.x, xB.y, xB.z, xB.w};
            float av[8] = {aA.x, aA.y, aA.z, aA.w, aB.x, aB.y, aB.z, aB.w};
#pragma unroll
            for (int i = 0; i < 8; ++i)
#pragma unroll
                for (int j = 0; j < 8; ++j)
                    acc[i][j] = fmaf(xv[i], av[j], acc[i][j]);
        }
    }
    float* vp = vpart + ((size_t)s * BATCH * DIM + (size_t)b * DIM) * KCL;
#pragma unroll
    for (int i = 0; i < 8; ++i) {
        float* row = vp + (size_t)(d0 + i) * KCL + k0;
        *(float4*)(row)     = make_float4(acc[i][0], acc[i][1], acc[i][2], acc[i][3]);
        *(float4*)(row + 4) = make_float4(acc[i][4], acc[i][5], acc[i][6], acc[i][7]);
    }
}

// ---------------- K3: split-reduce + C*a_sum + intra-normalize ----------------
// grid 256, block 256: 32 rows per block, 8 threads per row, float4 per thread.
__global__ __launch_bounds__(256) void k_norm1(const float* __restrict__ vpart,
                                               const float* __restrict__ a_sum,
                                               const float* __restrict__ Cc,
                                               float* __restrict__ out,
                                               float* __restrict__ ssq) {
    const int t = threadIdx.x;
    const int row = blockIdx.x * 32 + (t >> 3);  // 0..8191
    const int c = (t & 7) * 4;
    const int b = row >> 9;
    const int d = row & 511;

    float4 sum = make_float4(0.f, 0.f, 0.f, 0.f);
#pragma unroll 8
    for (int s = 0; s < SPLITS; ++s) {
        float4 p = *(const float4*)(vpart + (((size_t)s * BATCH * DIM + row) * KCL + c));
        sum.x += p.x; sum.y += p.y; sum.z += p.z; sum.w += p.w;
    }
    float4 cc = *(const float4*)(Cc + d * KCL + c);
    float4 as = *(const float4*)(a_sum + b * KCL + c);
    float4 v;
    v.x = sum.x + cc.x * as.x;
    v.y = sum.y + cc.y * as.y;
    v.z = sum.z + cc.z * as.z;
    v.w = sum.w + cc.w * as.w;

    float part = v.x * v.x + v.y * v.y + v.z * v.z + v.w * v.w;
    float ss = part;
    ss += __shfl_xor(ss, 1, 8);
    ss += __shfl_xor(ss, 2, 8);
    ss += __shfl_xor(ss, 4, 8);
    float inv = 1.f / fmaxf(sqrtf(ss), 1e-12f);
    v.x *= inv; v.y *= inv; v.z *= inv; v.w *= inv;
    *(float4*)(out + (size_t)row * KCL + c) = v;

    float bs = part * inv * inv;
    for (int off = 32; off > 0; off >>= 1) bs += __shfl_down(bs, off, 64);
    __shared__ float red[4];
    if ((t & 63) == 0) red[t >> 6] = bs;
    __syncthreads();
    if (t == 0) atomAddF(&ssq[b], red[0] + red[1] + red[2] + red[3]);
}

// ---------------- K4: final global L2 normalize ----------------
__global__ __launch_bounds__(256) void k_norm2(float* __restrict__ out,
                                               const float* __restrict__ ssq) {
    const int i4 = blockIdx.x * 256 + threadIdx.x;  // 0..65535
    const int b = i4 >> 12;
    float inv = 1.f / fmaxf(sqrtf(ssq[b]), 1e-12f);
    float4 v = *(float4*)(out + (size_t)i4 * 4);
    v.x *= inv; v.y *= inv; v.z *= inv; v.w *= inv;
    *(float4*)(out + (size_t)i4 * 4) = v;
}

extern "C" void kernel_launch(void* const* d_in, const int* in_sizes, int n_in,
                              void* d_out, int out_size, void* d_ws, size_t ws_size,
                              hipStream_t stream) {
    const float* x  = (const float*)d_in[0];   // (16,56,56,512)
    const float* Wc = (const float*)d_in[1];   // (512,32)
    const float* Cc = (const float*)d_in[2];   // (512,32)
    float* out = (float*)d_out;                // (16, 16384)

    // workspace layout (bytes):
    //   a     : N*K*4              = 6,422,528
    //   vpart : SPLITS*B*D*K*4     = 33,554,432  (pure stores, no init needed)
    //   a_sum : B*K*4              = 2,048   } zeroed
    //   ssq   : B*4                = 64      } zeroed
    char* ws = (char*)d_ws;
    float* a     = (float*)ws;
    float* vpart = (float*)(ws + 6422528);
    float* a_sum = (float*)(ws + 6422528 + 33554432);
    float* ssq   = (float*)(ws + 6422528 + 33554432 + 2048);

    hipMemsetAsync(a_sum, 0, 2048 + 64, stream);

    k_assign<<<dim3(49, 16), 256, 0, stream>>>(x, Wc, a, a_sum);
    k_ax    <<<dim3(SPLITS, 16), 256, 0, stream>>>(x, a, vpart);
    k_norm1 <<<256, 256, 0, stream>>>(vpart, a_sum, Cc, out, ssq);
    k_norm2 <<<256, 256, 0, stream>>>(out, ssq);
}